// Round 19
// baseline (98.141 us; speedup 1.0000x reference)
//
#include <hip/hip_runtime.h>
#include <hip/hip_bf16.h>

// MMD loss via single-plane fp16 MFMA Gram pass, fragment-major layout.
//   a16f[kb][row][8]: lane's fragment = 16B at ((kb*8192+row)*8), coalesced.
//   d2 = sq_i + sq_j - 2 dot (sq exact f32);  kernels = u+u^2+u^4+u^8+u^16.
// main = r18's (44us): 256 thr, 2x2 waves of 64x64, triangle 2080, LDS-free
//   free-running, unroll 4, setprio, Horner epilogue. UNTOUCHED hot loop.
// This round: launch chain 4 -> memset+2. bw_kernel folded into prep via
//   device-scope atomics (colsum f32, sumsq f64) + completion counter; last
//   prep block computes negc. Finalize folded into last main block via
//   atomicAdd + explicit vmcnt(0) ordering (completion at coherent point).
//   NO __threadfence anywhere (r16: agent fence = L2 invalidate, +16us/1000).
// T1 XCD swizzle (2080 % 8 == 0 -> bijective).

#define N_TOTAL 8192
#define B_HALF 4096
#define D_DIM 256
#define TILE 128
#define NTILE 64          // 8192/128
#define NTRI 2080         // 64*65/2

typedef float f32x16 __attribute__((ext_vector_type(16)));
typedef _Float16 f16x8 __attribute__((ext_vector_type(8)));

// meta block at ws+0 (memset to 0 each call, 1088 bytes):
//   [0]  double accum
//   [8]  double sumsq
//   [16] uint   cnt_prep
//   [20] uint   cnt_main
//   [64] float  colsum[256]
// negc (float) lives at [1152] — written by prep, NOT memset.

__device__ __forceinline__ const float* row_base(const float* src, const float* tgt, int r) {
    return (r < B_HALF) ? src + (size_t)r * D_DIM : tgt + (size_t)(r - B_HALF) * D_DIM;
}

// 256 blocks x 32 rows. sq + colsum/sumsq atomics + fragment-major convert.
// Last block (completion counter) computes negc in-block.
__global__ __launch_bounds__(256) void prep_kernel(const float* __restrict__ src,
                                                   const float* __restrict__ tgt,
                                                   _Float16* __restrict__ a16f,
                                                   float* __restrict__ sq,
                                                   char* __restrict__ meta) {
    double*   accum  = (double*)meta;           (void)accum;
    double*   sumsq  = (double*)(meta + 8);
    unsigned* cntp   = (unsigned*)(meta + 16);
    float*    colsum = (float*)(meta + 64);
    float*    negc   = (float*)(meta + 1152);

    __shared__ float cpl[4][D_DIM];   // per-wave column partials
    __shared__ int islast;
    int tid = threadIdx.x, w = tid >> 6, lane = tid & 63;
    int r0 = blockIdx.x * 32;

    // sq + column partials in ONE pass: wave handles 8 rows
    float c0 = 0.f, c1 = 0.f, c2 = 0.f, c3 = 0.f;
    float sq_part = 0.f;
    #pragma unroll
    for (int i = 0; i < 8; ++i) {
        int row = r0 + w * 8 + i;
        const float* rp = row_base(src, tgt, row);
        float4 v = ((const float4*)rp)[lane];
        c0 += v.x; c1 += v.y; c2 += v.z; c3 += v.w;
        float s = v.x*v.x + v.y*v.y + v.z*v.z + v.w*v.w;
        #pragma unroll
        for (int off = 32; off; off >>= 1) s += __shfl_down(s, off, 64);
        if (lane == 0) { sq[row] = s; sq_part += s; }
    }
    cpl[w][lane * 4 + 0] = c0;
    cpl[w][lane * 4 + 1] = c1;
    cpl[w][lane * 4 + 2] = c2;
    cpl[w][lane * 4 + 3] = c3;
    if (lane == 0) atomicAdd(sumsq, (double)sq_part);
    __syncthreads();
    atomicAdd(&colsum[tid], cpl[0][tid] + cpl[1][tid] + cpl[2][tid] + cpl[3][tid]);

    // __syncthreads drains vmcnt (compiler barrier semantics) -> this block's
    // atomics are complete at the coherent point before cnt increments.
    __syncthreads();
    if (tid == 0) {
        unsigned old = atomicAdd(cntp, 1u);
        islast = (old == 255u);
    }
    __syncthreads();
    if (islast) {
        // all 256 blocks' colsum/sumsq atomics complete -> compute negc
        __shared__ float red[256];
        float c = atomicAdd(&colsum[tid], 0.f);   // coherent read
        red[tid] = c * c;
        __syncthreads();
        for (int off = 128; off; off >>= 1) {
            if (tid < off) red[tid] += red[tid + off];
            __syncthreads();
        }
        if (tid == 0) {
            double ss = atomicAdd(sumsq, 0.0);    // coherent read
            double S1 = 2.0 * (double)N_TOTAL * ss - 2.0 * (double)red[0];
            double nn = (double)N_TOTAL * (double)N_TOTAL - (double)N_TOTAL;
            double bw = S1 / nn / 4.0;   // KERNEL_MUL^(KERNEL_NUM//2) = 4
            negc[0] = (float)(-1.4426950408889634 / (16.0 * bw));
        }
    }

    // fragment-major convert: wave-task = (kb, 64-row group), 4 per wave.
    int wg = blockIdx.x * 4 + w;                   // 0..1023
    #pragma unroll
    for (int i = 0; i < 4; ++i) {
        int t  = wg * 4 + i;                       // 0..4095
        int kb = t >> 7, rg = t & 127;
        int row = rg * 64 + lane;
        const float* rp = row_base(src, tgt, row) + kb * 8;
        float4 v0 = ((const float4*)rp)[0];
        float4 v1 = ((const float4*)rp)[1];
        _Float16 h[8] = {(_Float16)v0.x, (_Float16)v0.y, (_Float16)v0.z, (_Float16)v0.w,
                         (_Float16)v1.x, (_Float16)v1.y, (_Float16)v1.z, (_Float16)v1.w};
        *(f16x8*)(a16f + ((size_t)kb * N_TOTAL + row) * 8) = *(f16x8*)h;
    }
}

__global__ __launch_bounds__(256, 4) void mmd_main(const _Float16* __restrict__ a16f,
                                                   const float* __restrict__ sq,
                                                   char* __restrict__ meta,
                                                   float* __restrict__ out) {
    double*   accum = (double*)meta;
    unsigned* cntm  = (unsigned*)(meta + 20);
    const float* negc = (const float*)(meta + 1152);

    __shared__ float wsum[4];

    // T1: XCD swizzle (2080 % 8 == 0 -> bijective), then triangle decode (jt >= it)
    int b  = blockIdx.x;
    int bs = (b & 7) * (NTRI / 8) + (b >> 3);
    int it = 0, cum = 0;
    while (cum + (NTILE - it) <= bs) { cum += NTILE - it; ++it; }
    int jt = it + (bs - cum);

    int tid = threadIdx.x, lane = tid & 63, wid = tid >> 6;
    int wrow = wid >> 1, wcol = wid & 1;      // 2x2 wave grid; per-wave 64x64
    int rowA = it * TILE, rowB = jt * TILE;
    int c32 = lane & 31, khalf = lane >> 5;

    // fragment-major: lane fragment (kap, khalf): kb = kap*2+khalf,
    // 16B at ((kb*8192+row)*8). Consecutive lanes -> consecutive 16B.
    const _Float16* PA = a16f + (size_t)khalf * (N_TOTAL * 8)
                              + (size_t)(rowA + wrow * 64 + c32) * 8;
    const _Float16* PB = a16f + (size_t)khalf * (N_TOTAL * 8)
                              + (size_t)(rowB + wcol * 64 + c32) * 8;

    f32x16 acc[2][2] = {};

    #pragma unroll 4
    for (int kap = 0; kap < 16; ++kap) {      // K = 256 in steps of 16
        size_t ko = (size_t)kap * (N_TOTAL * 16);   // 2 k-blocks per step
        f16x8 af[2], bf[2];
        af[0] = *(const f16x8*)(PA + ko);
        af[1] = *(const f16x8*)(PA + ko + 32 * 8);
        bf[0] = *(const f16x8*)(PB + ko);
        bf[1] = *(const f16x8*)(PB + ko + 32 * 8);
        __builtin_amdgcn_s_setprio(1);        // T5: free-running waves regime
        #pragma unroll
        for (int mt = 0; mt < 2; ++mt)
            #pragma unroll
            for (int nt = 0; nt < 2; ++nt)
                acc[mt][nt] = __builtin_amdgcn_mfma_f32_32x32x16_f16(af[mt], bf[nt], acc[mt][nt], 0, 0, 0);
        __builtin_amdgcn_s_setprio(0);
    }

    // Horner epilogue: e = nc*si + nc*sj - 2nc*acc; u = exp2(min(e,0));
    // S = u + u^2(1 + u^2(1 + u^4(1 + u^8))).
    // C/D layout: col=lane&31, row=(reg&3)+8*(reg>>2)+4*khalf.
    float nc = *negc;
    float m2nc = -2.f * nc;
    float sj1[2];
    #pragma unroll
    for (int nt = 0; nt < 2; ++nt)
        sj1[nt] = nc * sq[rowB + wcol * 64 + nt * 32 + c32];
    float tu = 0.f, t2 = 0.f;
    #pragma unroll
    for (int mt = 0; mt < 2; ++mt) {
        #pragma unroll
        for (int reg = 0; reg < 16; ++reg) {
            int i = rowA + wrow * 64 + mt * 32 + (reg & 3) + 8 * (reg >> 2) + 4 * khalf;
            float si1 = nc * sq[i];
            #pragma unroll
            for (int nt = 0; nt < 2; ++nt) {
                float e  = fminf(fmaf(m2nc, acc[mt][nt][reg], si1 + sj1[nt]), 0.f);
                float u  = exp2f(e);
                float u2 = u * u, u4 = u2 * u2, u8 = u4 * u4;
                float in2 = fmaf(u4, 1.f + u8, 1.f);
                float in3 = fmaf(u2, in2, 1.f);
                tu += u;
                t2  = fmaf(u2, in3, t2);
            }
        }
    }
    float scale = (((it < 32) == (jt < 32)) ? 1.f : -1.f) * ((it == jt) ? 1.f : 2.f);
    float tsum = (tu + t2) * scale;

    #pragma unroll
    for (int off = 32; off; off >>= 1) tsum += __shfl_down(tsum, off, 64);
    if (lane == 0) wsum[wid] = tsum;
    __syncthreads();
    if (tid == 0) {
        float t = wsum[0] + wsum[1] + wsum[2] + wsum[3];
        atomicAdd(accum, (double)t);
        // order: my accum-add COMPLETE at coherent point before cnt-add issues.
        // (plain vmcnt wait — NOT __threadfence; no L2 invalidate.)
        asm volatile("s_waitcnt vmcnt(0)" ::: "memory");
        unsigned old = atomicAdd(cntm, 1u);
        if (old == NTRI - 1) {                 // last block: fused finalize
            double v = atomicAdd(accum, 0.0);  // coherent read of full sum
            out[0] = (float)(v / ((double)B_HALF * (double)B_HALF));
        }
    }
}

extern "C" void kernel_launch(void* const* d_in, const int* in_sizes, int n_in,
                              void* d_out, int out_size, void* d_ws, size_t ws_size,
                              hipStream_t stream) {
    const float* src = (const float*)d_in[0];
    const float* tgt = (const float*)d_in[1];
    float* out = (float*)d_out;

    char* ws = (char*)d_ws;
    char*     meta = ws;                                  // 1088B zeroed + negc@1152
    float*    sq   = (float*)(ws + 4096);                 // 32 KB
    _Float16* a16f = (_Float16*)(ws + 65536);             // 4 MB plane (fragment-major)

    hipMemsetAsync(meta, 0, 1088, stream);                // accum/sumsq/cnts/colsum
    prep_kernel<<<256, 256, 0, stream>>>(src, tgt, a16f, sq, meta);
    mmd_main<<<NTRI, 256, 0, stream>>>(a16f, sq, meta, out);
}

// Round 20
// 75.132 us; speedup vs baseline: 1.3062x; 1.3062x over previous
//
#include <hip/hip_runtime.h>
#include <hip/hip_bf16.h>

// MMD loss via single-plane fp16 MFMA Gram pass, fragment-major layout.
//   a16f[kb][row][8]: lane's fragment = 16B at ((kb*8192+row)*8), coalesced.
//   d2 = sq_i + sq_j - 2 dot (sq exact f32);  kernels = u+u^2+u^4+u^8+u^16.
// main = r18's measured 44-45us kernel, UNTOUCHED: 256 thr, 2x2 waves of
//   64x64, triangle 2080, LDS-free free-running, unroll 4, setprio, Horner
//   epilogue, SINGLE accum atomic tail, separate finalize kernel.
// Ledger: fused finalize tail (accum-atomic -> ordered wait -> cnt-atomic,
//   same cacheline, 2080x) costs ~24us regardless of fence type (r15/16/19,
//   WRITE 130KB signature). Separate 1-block finalize ~2-4us. Keep separate.
// prep = r19's (validated): colpart+sumsq via device atomics + completion
//   counter; last prep block computes negc in-block. Kills bw_kernel launch.
// T1 XCD swizzle (2080 % 8 == 0 -> bijective).

#define N_TOTAL 8192
#define B_HALF 4096
#define D_DIM 256
#define TILE 128
#define NTILE 64          // 8192/128
#define NTRI 2080         // 64*65/2

typedef float f32x16 __attribute__((ext_vector_type(16)));
typedef _Float16 f16x8 __attribute__((ext_vector_type(8)));

// meta block at ws+0 (memset to 0 each call, 1088 bytes):
//   [0]  double accum
//   [8]  double sumsq
//   [16] uint   cnt_prep
//   [64] float  colsum[256]
// negc (float) at [1152] — written by prep's last block, NOT memset.

__device__ __forceinline__ const float* row_base(const float* src, const float* tgt, int r) {
    return (r < B_HALF) ? src + (size_t)r * D_DIM : tgt + (size_t)(r - B_HALF) * D_DIM;
}

// 256 blocks x 32 rows. sq + colsum/sumsq atomics + fragment-major convert.
// Last block (completion counter) computes negc in-block.
__global__ __launch_bounds__(256) void prep_kernel(const float* __restrict__ src,
                                                   const float* __restrict__ tgt,
                                                   _Float16* __restrict__ a16f,
                                                   float* __restrict__ sq,
                                                   char* __restrict__ meta) {
    double*   sumsq  = (double*)(meta + 8);
    unsigned* cntp   = (unsigned*)(meta + 16);
    float*    colsum = (float*)(meta + 64);
    float*    negc   = (float*)(meta + 1152);

    __shared__ float cpl[4][D_DIM];   // per-wave column partials
    __shared__ int islast;
    int tid = threadIdx.x, w = tid >> 6, lane = tid & 63;
    int r0 = blockIdx.x * 32;

    // sq + column partials in ONE pass: wave handles 8 rows
    float c0 = 0.f, c1 = 0.f, c2 = 0.f, c3 = 0.f;
    float sq_part = 0.f;
    #pragma unroll
    for (int i = 0; i < 8; ++i) {
        int row = r0 + w * 8 + i;
        const float* rp = row_base(src, tgt, row);
        float4 v = ((const float4*)rp)[lane];
        c0 += v.x; c1 += v.y; c2 += v.z; c3 += v.w;
        float s = v.x*v.x + v.y*v.y + v.z*v.z + v.w*v.w;
        #pragma unroll
        for (int off = 32; off; off >>= 1) s += __shfl_down(s, off, 64);
        if (lane == 0) { sq[row] = s; sq_part += s; }
    }
    cpl[w][lane * 4 + 0] = c0;
    cpl[w][lane * 4 + 1] = c1;
    cpl[w][lane * 4 + 2] = c2;
    cpl[w][lane * 4 + 3] = c3;
    if (lane == 0) atomicAdd(sumsq, (double)sq_part);
    __syncthreads();
    atomicAdd(&colsum[tid], cpl[0][tid] + cpl[1][tid] + cpl[2][tid] + cpl[3][tid]);

    // barrier drains outstanding ops -> this block's atomics complete before cnt.
    __syncthreads();
    if (tid == 0) {
        unsigned old = atomicAdd(cntp, 1u);
        islast = (old == 255u);
    }
    __syncthreads();
    if (islast) {
        __shared__ float red[256];
        float c = atomicAdd(&colsum[tid], 0.f);   // coherent read
        red[tid] = c * c;
        __syncthreads();
        for (int off = 128; off; off >>= 1) {
            if (tid < off) red[tid] += red[tid + off];
            __syncthreads();
        }
        if (tid == 0) {
            double ss = atomicAdd(sumsq, 0.0);    // coherent read
            double S1 = 2.0 * (double)N_TOTAL * ss - 2.0 * (double)red[0];
            double nn = (double)N_TOTAL * (double)N_TOTAL - (double)N_TOTAL;
            double bw = S1 / nn / 4.0;   // KERNEL_MUL^(KERNEL_NUM//2) = 4
            negc[0] = (float)(-1.4426950408889634 / (16.0 * bw));
        }
    }

    // fragment-major convert: wave-task = (kb, 64-row group), 4 per wave.
    int wg = blockIdx.x * 4 + w;                   // 0..1023
    #pragma unroll
    for (int i = 0; i < 4; ++i) {
        int t  = wg * 4 + i;                       // 0..4095
        int kb = t >> 7, rg = t & 127;
        int row = rg * 64 + lane;
        const float* rp = row_base(src, tgt, row) + kb * 8;
        float4 v0 = ((const float4*)rp)[0];
        float4 v1 = ((const float4*)rp)[1];
        _Float16 h[8] = {(_Float16)v0.x, (_Float16)v0.y, (_Float16)v0.z, (_Float16)v0.w,
                         (_Float16)v1.x, (_Float16)v1.y, (_Float16)v1.z, (_Float16)v1.w};
        *(f16x8*)(a16f + ((size_t)kb * N_TOTAL + row) * 8) = *(f16x8*)h;
    }
}

__global__ __launch_bounds__(256, 4) void mmd_main(const _Float16* __restrict__ a16f,
                                                   const float* __restrict__ sq,
                                                   const char* __restrict__ meta,
                                                   double* __restrict__ accum) {
    const float* negc = (const float*)(meta + 1152);
    __shared__ float wsum[4];

    // T1: XCD swizzle (2080 % 8 == 0 -> bijective), then triangle decode (jt >= it)
    int b  = blockIdx.x;
    int bs = (b & 7) * (NTRI / 8) + (b >> 3);
    int it = 0, cum = 0;
    while (cum + (NTILE - it) <= bs) { cum += NTILE - it; ++it; }
    int jt = it + (bs - cum);

    int tid = threadIdx.x, lane = tid & 63, wid = tid >> 6;
    int wrow = wid >> 1, wcol = wid & 1;      // 2x2 wave grid; per-wave 64x64
    int rowA = it * TILE, rowB = jt * TILE;
    int c32 = lane & 31, khalf = lane >> 5;

    // fragment-major: lane fragment (kap, khalf): kb = kap*2+khalf,
    // 16B at ((kb*8192+row)*8). Consecutive lanes -> consecutive 16B.
    const _Float16* PA = a16f + (size_t)khalf * (N_TOTAL * 8)
                              + (size_t)(rowA + wrow * 64 + c32) * 8;
    const _Float16* PB = a16f + (size_t)khalf * (N_TOTAL * 8)
                              + (size_t)(rowB + wcol * 64 + c32) * 8;

    f32x16 acc[2][2] = {};

    #pragma unroll 4
    for (int kap = 0; kap < 16; ++kap) {      // K = 256 in steps of 16
        size_t ko = (size_t)kap * (N_TOTAL * 16);   // 2 k-blocks per step
        f16x8 af[2], bf[2];
        af[0] = *(const f16x8*)(PA + ko);
        af[1] = *(const f16x8*)(PA + ko + 32 * 8);
        bf[0] = *(const f16x8*)(PB + ko);
        bf[1] = *(const f16x8*)(PB + ko + 32 * 8);
        __builtin_amdgcn_s_setprio(1);        // T5: free-running waves regime
        #pragma unroll
        for (int mt = 0; mt < 2; ++mt)
            #pragma unroll
            for (int nt = 0; nt < 2; ++nt)
                acc[mt][nt] = __builtin_amdgcn_mfma_f32_32x32x16_f16(af[mt], bf[nt], acc[mt][nt], 0, 0, 0);
        __builtin_amdgcn_s_setprio(0);
    }

    // Horner epilogue: e = nc*si + nc*sj - 2nc*acc; u = exp2(min(e,0));
    // S = u + u^2(1 + u^2(1 + u^4(1 + u^8))).
    // C/D layout: col=lane&31, row=(reg&3)+8*(reg>>2)+4*khalf.
    float nc = *negc;
    float m2nc = -2.f * nc;
    float sj1[2];
    #pragma unroll
    for (int nt = 0; nt < 2; ++nt)
        sj1[nt] = nc * sq[rowB + wcol * 64 + nt * 32 + c32];
    float tu = 0.f, t2 = 0.f;
    #pragma unroll
    for (int mt = 0; mt < 2; ++mt) {
        #pragma unroll
        for (int reg = 0; reg < 16; ++reg) {
            int i = rowA + wrow * 64 + mt * 32 + (reg & 3) + 8 * (reg >> 2) + 4 * khalf;
            float si1 = nc * sq[i];
            #pragma unroll
            for (int nt = 0; nt < 2; ++nt) {
                float e  = fminf(fmaf(m2nc, acc[mt][nt][reg], si1 + sj1[nt]), 0.f);
                float u  = exp2f(e);
                float u2 = u * u, u4 = u2 * u2, u8 = u4 * u4;
                float in2 = fmaf(u4, 1.f + u8, 1.f);
                float in3 = fmaf(u2, in2, 1.f);
                tu += u;
                t2  = fmaf(u2, in3, t2);
            }
        }
    }
    float scale = (((it < 32) == (jt < 32)) ? 1.f : -1.f) * ((it == jt) ? 1.f : 2.f);
    float tsum = (tu + t2) * scale;

    #pragma unroll
    for (int off = 32; off; off >>= 1) tsum += __shfl_down(tsum, off, 64);
    if (lane == 0) wsum[wid] = tsum;
    __syncthreads();
    if (tid == 0) {
        float t = wsum[0] + wsum[1] + wsum[2] + wsum[3];
        atomicAdd(accum, (double)t);     // single atomic; NO ordered tail
    }
}

__global__ void finalize_kernel(const double* __restrict__ accum, float* __restrict__ out) {
    out[0] = (float)(accum[0] / ((double)B_HALF * (double)B_HALF));
}

extern "C" void kernel_launch(void* const* d_in, const int* in_sizes, int n_in,
                              void* d_out, int out_size, void* d_ws, size_t ws_size,
                              hipStream_t stream) {
    const float* src = (const float*)d_in[0];
    const float* tgt = (const float*)d_in[1];
    float* out = (float*)d_out;

    char* ws = (char*)d_ws;
    char*     meta  = ws;                                 // 1088B zeroed; negc @1152
    double*   accum = (double*)ws;                        // meta[0]
    float*    sq    = (float*)(ws + 4096);                // 32 KB
    _Float16* a16f  = (_Float16*)(ws + 65536);            // 4 MB plane (fragment-major)

    hipMemsetAsync(meta, 0, 1088, stream);                // accum/sumsq/cnt/colsum
    prep_kernel<<<256, 256, 0, stream>>>(src, tgt, a16f, sq, meta);
    mmd_main<<<NTRI, 256, 0, stream>>>(a16f, sq, meta, accum);
    finalize_kernel<<<1, 1, 0, stream>>>(accum, out);
}